// Round 13
// baseline (17419.307 us; speedup 1.0000x reference)
//
#include <hip/hip_runtime.h>
#include <hip/hip_bf16.h>

#define NSL 64
#define NPX 16384   // 128*128
#define VN  2097152 // 128^3
#define PCL 16900   // 130*130 lattice layer
#define PCS 50700   // 3*PCL per slice
#define PCN 3244800 // NSL*PCS

// ---------------- prep: per-slice R,t (fp32 inputs) ----------------
__global__ void k_prep(const float* __restrict__ tr, const float* __restrict__ psf,
                       float* __restrict__ Rm, float* __restrict__ pw)
{
  int n = threadIdx.x;
  if (n < 27) pw[n] = psf[n];
  if (n >= NSL) return;
  #pragma unroll
  for (int i = 0; i < 3; i++){
    #pragma unroll
    for (int j = 0; j < 3; j++) Rm[n*12 + i*3 + j] = tr[n*12 + i*4 + j];
    Rm[n*12 + 9 + i] = tr[n*12 + i*4 + 3];
  }
}

// ---------------- mask ----------------
__global__ void k_mask(const float* __restrict__ slices, float* __restrict__ mask)
{
  int gid = blockIdx.x*256 + threadIdx.x;
  if (gid >= NSL*NPX) return;
  int n = gid >> 14, p = gid & 16383;
  int py = p >> 7, px = p & 127;
  const float* s = slices + n*NPX;
  bool any = false;
  for (int dy = -1; dy <= 1; dy++){
    int yy = py + dy;
    if ((unsigned)yy >= 128u) continue;
    for (int dx = -1; dx <= 1; dx++){
      int xx = px + dx;
      if ((unsigned)xx >= 128u) continue;
      any = any || (s[yy*128 + xx] > 0.f);
    }
  }
  mask[gid] = any ? 1.f : 0.f;
}

__global__ void k_volcopy(const float* __restrict__ v, float* __restrict__ o)
{
  int gid = blockIdx.x*256 + threadIdx.x;
  if (gid < VN) o[gid] = v[gid];
}

__global__ void k_copy0(const float* __restrict__ slices, float* __restrict__ z)
{
  int gid = blockIdx.x*256 + threadIdx.x;
  if (gid >= NSL*NPX) return;
  int n = gid >> 14, p = gid & 16383;
  z[n*2*NPX + p] = slices[gid];
}

// premultiply slice values by mask (and optional per-slice scale)
__global__ void k_premul(const float* __restrict__ s, const float* __restrict__ mask,
                         const float* __restrict__ ps, float* __restrict__ o)
{
  int gid = blockIdx.x*256 + threadIdx.x;
  if (gid >= NSL*NPX) return;
  float v = s[gid] * mask[gid];
  if (ps) v *= ps[gid >> 14];
  o[gid] = v;
}

// sscr[n][p] = z2[n][p] * ps[n]  (reuse prologue A(x0)*mask, which survives convs)
__global__ void k_zscale(const float* __restrict__ z, const float* __restrict__ ps,
                         float* __restrict__ out)
{
  int gid = blockIdx.x*256 + threadIdx.x;
  if (gid >= NSL*NPX) return;
  int n = gid >> 14, p = gid & 16383;
  out[gid] = z[n*2*NPX + NPX + p] * ps[n];
}

// ---------------- trilinear gather helper ----------------
__device__ __forceinline__ float lerpf(float a, float b, float t){ return fmaf(t, b-a, a); }

__device__ __forceinline__ float tri_gather(const float* __restrict__ vol, float x, float y, float z)
{
  float xf = floorf(x), yf = floorf(y), zf = floorf(z);
  int x0 = (int)xf, y0 = (int)yf, z0 = (int)zf;
  float fx = x - xf, fy = y - yf, fz = z - zf;
  if ((unsigned)x0 < 127u && (unsigned)y0 < 127u && (unsigned)z0 < 127u){
    const float* p = vol + (z0*128 + y0)*128 + x0;
    float c00 = lerpf(p[0],     p[1],     fx);
    float c01 = lerpf(p[128],   p[129],   fx);
    float c10 = lerpf(p[16384], p[16385], fx);
    float c11 = lerpf(p[16512], p[16513], fx);
    return lerpf(lerpf(c00, c01, fy), lerpf(c10, c11, fy), fz);
  }
  float gx0 = 1.f - fx, gy0 = 1.f - fy, gz0 = 1.f - fz;
  bool vx0 = (unsigned)x0 < 128u, vx1 = (unsigned)(x0+1) < 128u;
  bool vy0 = (unsigned)y0 < 128u, vy1 = (unsigned)(y0+1) < 128u;
  bool vz0 = (unsigned)z0 < 128u, vz1 = (unsigned)(z0+1) < 128u;
  int i0 = (z0*128 + y0)*128 + x0;
  float acc = 0.f;
  if (vz0){
    if (vy0){
      if (vx0) acc += gx0*gy0*gz0 * vol[i0];
      if (vx1) acc += fx *gy0*gz0 * vol[i0+1];
    }
    if (vy1){
      if (vx0) acc += gx0*fy*gz0 * vol[i0+128];
      if (vx1) acc += fx *fy*gz0 * vol[i0+129];
    }
  }
  if (vz1){
    int i1 = i0 + 16384;
    if (vy0){
      if (vx0) acc += gx0*gy0*fz * vol[i1];
      if (vx1) acc += fx *gy0*fz * vol[i1+1];
    }
    if (vy1){
      if (vx0) acc += gx0*fy*fz * vol[i1+128];
      if (vx1) acc += fx *fy*fz * vol[i1+129];
    }
  }
  return acc;
}

// ---------------- A (forward), lattice-factored ----------------
__global__ void k_gvol(const float* __restrict__ vol, const float* __restrict__ Rm,
                       float* __restrict__ out)
{
  int gid = blockIdx.x*256 + threadIdx.x;
  if (gid >= PCN) return;
  int n = gid / PCS;
  int r = gid % PCS;
  int w = r / PCL - 1;
  int q = r % PCL;
  int v = q / 130 - 1, u = q % 130 - 1;
  const float* R = Rm + n*12;
  float fu = (float)u - 63.5f, fv = (float)v - 63.5f, fw = (float)w;
  float x = R[0]*fu + R[1]*fv + R[2]*fw + R[9]  + 63.5f;
  float y = R[3]*fu + R[4]*fv + R[5]*fw + R[10] + 63.5f;
  float z = R[6]*fu + R[7]*fv + R[8]*fw + R[11] + 63.5f;
  out[gid] = tri_gather(vol, x, y, z);
}

__global__ void k_gcorr(const float* __restrict__ G, const float* __restrict__ pw,
                        const float* __restrict__ mask, const float* __restrict__ ps,
                        float* __restrict__ out, int outStride, int outOff)
{
  __shared__ float spw[27];
  if (threadIdx.x < 27) spw[threadIdx.x] = pw[threadIdx.x];
  __syncthreads();
  int gid = blockIdx.x*256 + threadIdx.x;   // exactly NSL*NPX threads
  int n = gid >> 14;
  int p = gid & 16383;
  int py = p >> 7, px = p & 127;
  const float* Gn = G + n*PCS;
  float acc = 0.f;
  #pragma unroll
  for (int k = 0; k < 27; k++){
    int ox = k % 3, oy = (k/3) % 3, oz = k/9;   // == offset+1
    acc += spw[k] * Gn[oz*PCL + (py+oy)*130 + (px+ox)];
  }
  float val = acc * mask[gid];
  if (ps) val *= ps[n];
  out[n*outStride + outOff + p] = val;
}

// ---------------- PSF pre-correlation for the adjoint ----------------
__global__ void k_pcorr(const float* __restrict__ val, const float* __restrict__ pw,
                        float* __restrict__ out)
{
  int gid = blockIdx.x*256 + threadIdx.x;
  if (gid >= PCN) return;
  int n = gid / PCS;
  int r = gid % PCS;
  int l = r / PCL;
  int q = r % PCL;
  int my = q / 130 - 1, mx = q % 130 - 1;
  const float* vs = val + n*NPX;
  const float* pg = pw + l*9;
  float inner = 0.f;
  #pragma unroll
  for (int oy = -1; oy <= 1; oy++){
    int qy = my - oy;
    if ((unsigned)qy >= 128u) continue;
    const float* vrow = vs + qy*128;
    const float* pr = pg + (oy+1)*3;
    #pragma unroll
    for (int ox = -1; ox <= 1; ox++){
      int qx = mx - ox;
      if ((unsigned)qx >= 128u) continue;
      inner += pr[ox+1] * vrow[qx];
    }
  }
  out[gid] = inner;
}

// ---------------- At: adjoint in GATHER form (atomic-free) ----------------
__global__ __launch_bounds__(256, 4) void k_sadj(
    const float* __restrict__ pcor,  // [NSL][3][130][130]
    const float* __restrict__ Rm,    // [NSL][12]
    float* __restrict__ out)         // [VN], overwritten
{
  __shared__ float sR[NSL*12];
  __shared__ int   slist[NSL];
  __shared__ int   scnt;
  int tid = threadIdx.x;
  for (int i = tid; i < NSL*12; i += 256) sR[i] = Rm[i];
  __syncthreads();

  int b  = blockIdx.x;
  int bx = (b & 15) * 8;
  int by = ((b >> 4) & 15) * 8;
  int bz = (b >> 8) * 4;

  if (tid < 64){
    const float* R = &sR[tid*12];
    float axc = ((float)bx + 3.5f) - 63.5f - R[9];
    float ayc = ((float)by + 3.5f) - 63.5f - R[10];
    float azc = ((float)bz + 1.5f) - 63.5f - R[11];
    float Zc = R[2]*axc + R[5]*ayc + R[8]*azc;
    float rZ = fabsf(R[2])*3.5f + fabsf(R[5])*3.5f + fabsf(R[8])*1.5f;
    bool ok = fabsf(Zc) < 2.7321f + rZ;
    if (ok){
      float Pc = R[0]*axc + R[3]*ayc + R[6]*azc + 63.5f;
      float rP = fabsf(R[0])*3.5f + fabsf(R[3])*3.5f + fabsf(R[6])*1.5f;
      float Qc = R[1]*axc + R[4]*ayc + R[7]*azc + 63.5f;
      float rQ = fabsf(R[1])*3.5f + fabsf(R[4])*3.5f + fabsf(R[7])*1.5f;
      ok = (Pc + rP > -2.7321f) && (Pc - rP < 130.7321f)
        && (Qc + rQ > -2.7321f) && (Qc - rQ < 130.7321f);
    }
    unsigned long long m = __ballot(ok);
    if (ok) slist[__popcll(m & ((1ull << tid) - 1ull))] = tid;
    if (tid == 0) scnt = (int)__popcll(m);
  }
  __syncthreads();
  int cnt = scnt;

  int lx = tid & 7, ly = (tid >> 3) & 7, lz = tid >> 6;
  int vx = bx + lx, vy = by + ly, vz = bz + lz;

  float cvx = (float)vx - 63.5f;
  float cvy = (float)vy - 63.5f;
  float cvz = (float)vz - 63.5f;

  float acc = 0.f;
  for (int i = 0; i < cnt; i++){
    int n = slist[i];
    const float* R = &sR[n*12];
    float ax = cvx - R[9], ay = cvy - R[10], az = cvz - R[11]; // v - t - ctr
    float Z = R[2]*ax + R[5]*ay + R[8]*az;
    if (fabsf(Z) >= 2.7321f) continue;
    float P = R[0]*ax + R[3]*ay + R[6]*az + 63.5f;
    float Q = R[1]*ax + R[4]*ay + R[7]*az + 63.5f;
    if (P <= -2.7321f || P >= 130.7321f || Q <= -2.7321f || Q >= 130.7321f) continue;
    const float* pc = pcor + n*PCS;

    #pragma unroll
    for (int mz = -1; mz <= 1; mz++){
      float dz = (float)mz - Z;
      float rem2 = 3.f - dz*dz;
      if (rem2 <= 0.f) continue;
      float sy = sqrtf(rem2);
      int my0 = (int)ceilf(Q - sy), my1 = (int)floorf(Q + sy);
      if (my0 < -1) my0 = -1;
      if (my1 > 128) my1 = 128;
      const float* pl = pc + (mz+1)*PCL;
      for (int my = my0; my <= my1; my++){
        float dy = (float)my - Q;
        float rem1 = rem2 - dy*dy;
        if (rem1 <= 0.f) continue;
        float sx = sqrtf(rem1);
        int mx0 = (int)ceilf(P - sx), mx1 = (int)floorf(P + sx);
        if (mx0 < -1) mx0 = -1;
        if (mx1 > 128) mx1 = 128;
        float dx = (float)mx0 - P;
        float rx = R[0]*dx + R[1]*dy + R[2]*dz;
        float ry = R[3]*dx + R[4]*dy + R[5]*dz;
        float rz = R[6]*dx + R[7]*dy + R[8]*dz;
        const float* crow = pl + (my+1)*130 + (mx0+1);
        for (int mx = mx0; mx <= mx1; mx++){
          float w3 = fmaxf(1.f - fabsf(rx), 0.f)
                   * fmaxf(1.f - fabsf(ry), 0.f)
                   * fmaxf(1.f - fabsf(rz), 0.f);
          if (w3 > 0.f) acc += w3 * crow[mx - mx0];
          rx += R[0]; ry += R[3]; rz += R[6];
        }
      }
    }
  }
  out[(vz*128 + vy)*128 + vx] = acc;
}

// ---------------- tiled conv (LDS-staged input) — used only for conv1 (Cin=2) ----
template<int K, int S, int TILE, int CC, int COT>
__global__ __launch_bounds__(256, 2) void k_convt(
    const float* __restrict__ in, const float* __restrict__ wt,
    const float* __restrict__ res, float* __restrict__ out,
    int Cin, int Hin, int Cout, int Hout,
    int pad, int relu, int nBG, int spTiles)
{
  constexpr int BPB  = 1024 / (TILE*TILE);
  constexpr int ITX  = (K==1) ? TILE : (TILE-1)*S + K;
  constexpr int ITP  = ITX | 1;
  constexpr int KK   = K*K;
  constexpr int PERB = TILE*TILE/4;
  constexpr int RS   = (K==1) ? 1 : S;
  constexpr int NIN  = (CC*ITX*ITX + PERB - 1)/PERB;
  constexpr int NWT  = (COT*CC*KK + 255)/256;

  __shared__ float sIn[BPB*CC*ITX*ITP];
  __shared__ float sW[CC*KK*COT];

  int tid = threadIdx.x;
  int bl  = tid / PERB;
  int t2  = tid % PERB;
  int tx  = t2 % TILE;
  int tyq = (t2 / TILE) * 4;

  int bid = blockIdx.x;
  int spT = bid % spTiles; bid /= spTiles;
  int bG  = bid % nBG;     bid /= nBG;
  int coT = bid;
  int b0  = bG * BPB;

  int tpr = Hout / TILE;
  int ox0 = (spT % tpr) * TILE;
  int oy0 = (spT / tpr) * TILE;
  int co0 = coT * COT;
  int ix0 = ox0*S - pad;
  int iy0 = oy0*S - pad;

  float acc[COT*4];
  #pragma unroll
  for (int i = 0; i < COT*4; i++) acc[i] = 0.f;

  for (int ci0 = 0; ci0 < Cin; ci0 += CC){
    #pragma unroll
    for (int it = 0; it < NWT; it++){
      int i = tid + it*256;
      if (i < COT*CC*KK){
        int co = i / (CC*KK);
        int r  = i % (CC*KK);
        sW[r*COT + co] = wt[((size_t)(co0+co)*Cin + ci0 + r/KK)*KK + (r % KK)];
      }
    }
    #pragma unroll
    for (int it = 0; it < NIN; it++){
      int i = t2 + it*PERB;
      if (i < CC*ITX*ITX){
        int cc = i / (ITX*ITX);
        int r  = i % (ITX*ITX);
        int yy = r / ITX, xx = r % ITX;
        int gy = (K==1) ? iy0 + yy*S : iy0 + yy;
        int gx = (K==1) ? ix0 + xx*S : ix0 + xx;
        float v = 0.f;
        if ((unsigned)gy < (unsigned)Hin && (unsigned)gx < (unsigned)Hin)
          v = in[(((size_t)(b0+bl)*Cin + ci0+cc)*Hin + gy)*Hin + gx];
        sIn[((bl*CC + cc)*ITX + yy)*ITP + xx] = v;
      }
    }
    __syncthreads();

    #pragma unroll
    for (int cc = 0; cc < CC; cc++){
      const float* ip = &sIn[(bl*CC + cc)*ITX*ITP];
      #pragma unroll
      for (int ky = 0; ky < K; ky++){
        #pragma unroll
        for (int kx = 0; kx < K; kx++){
          int xi = (K==1) ? tx : tx*S + kx;
          int yb = (K==1) ? tyq : tyq*S + ky;
          float v0 = ip[(yb       )*ITP + xi];
          float v1 = ip[(yb +   RS)*ITP + xi];
          float v2 = ip[(yb + 2*RS)*ITP + xi];
          float v3 = ip[(yb + 3*RS)*ITP + xi];
          const float4* wv = (const float4*)&sW[(cc*KK + ky*K + kx)*COT];
          #pragma unroll
          for (int g = 0; g < COT/4; g++){
            float4 w = wv[g];
            acc[(g*4+0)*4+0] += w.x*v0; acc[(g*4+0)*4+1] += w.x*v1;
            acc[(g*4+0)*4+2] += w.x*v2; acc[(g*4+0)*4+3] += w.x*v3;
            acc[(g*4+1)*4+0] += w.y*v0; acc[(g*4+1)*4+1] += w.y*v1;
            acc[(g*4+1)*4+2] += w.y*v2; acc[(g*4+1)*4+3] += w.y*v3;
            acc[(g*4+2)*4+0] += w.z*v0; acc[(g*4+2)*4+1] += w.z*v1;
            acc[(g*4+2)*4+2] += w.z*v2; acc[(g*4+2)*4+3] += w.z*v3;
            acc[(g*4+3)*4+0] += w.w*v0; acc[(g*4+3)*4+1] += w.w*v1;
            acc[(g*4+3)*4+2] += w.w*v2; acc[(g*4+3)*4+3] += w.w*v3;
          }
        }
      }
    }
    __syncthreads();
  }

  int b = b0 + bl;
  #pragma unroll
  for (int co = 0; co < COT; co++){
    size_t base = (((size_t)b*Cout + co0+co)*Hout + oy0 + tyq)*Hout + ox0 + tx;
    #pragma unroll
    for (int r = 0; r < 4; r++){
      float v = acc[co*4 + r];
      if (res) v += res[base + (size_t)r*Hout];
      if (relu) v = fmaxf(v, 0.f);
      out[base + (size_t)r*Hout] = v;
    }
  }
}

// ---------------- direct conv (input from L1/L2, weights-only LDS) ----------------
// R6 proven inner loop: inline per-tap loads pipeline under FMAs.
// KNOWN CEILINGS (do not cross):
//  - acc register ceiling: COT*4 <= 64 (R8: acc[128] spilled, 5x slowdown)
//  - no register strip reuse (R7: WAR hazard serialized loads, -16%)
//  - COT=16/grid-512 is the param-space optimum (R12: COT halved -> grid
//    1024 but occupancy stuck ~2 blocks/CU, per-block overhead doubled, +28%)
// swz: XCD-aware bijective block swizzle (R10: FETCH -28%, timing-neutral).
// R13: launch_bounds min-waves 2 -> 4 (VGPR already exactly 128 = 4-wave
// boundary; tests whether the occupancy hint was the ~8 waves/CU cap).
template<int K, int S, int TILE, int COT, int CCW>
__global__ __launch_bounds__(256, 4) void k_convd(
    const float* __restrict__ in, const float* __restrict__ wt,
    const float* __restrict__ res, float* __restrict__ out,
    int Cin, int Hin, int Cout, int Hout,
    int pad, int relu, int nBG, int spTiles, int swz)
{
  constexpr int PERB = TILE*TILE/4;
  constexpr int BPB  = 1024 / (TILE*TILE);
  constexpr int KK   = K*K;
  constexpr int NW   = (CCW*KK*COT + 255)/256;

  __shared__ float sW[CCW*KK*COT];

  int tid = threadIdx.x;
  int bl  = tid / PERB;
  int t2  = tid % PERB;
  int tx  = t2 % TILE;
  int tyq = (t2 / TILE) * 4;

  int bid = blockIdx.x;
  int spT, bG, coT;
  if (swz){
    int nCo = Cout / COT;
    int u = bid & 7; bid >>= 3;
    coT = bid % nCo; bid /= nCo;
    int tile = bid * 8 + u;        // [0, spTiles*nBG)
    spT = tile % spTiles;
    bG  = tile / spTiles;
  } else {
    spT = bid % spTiles; bid /= spTiles;
    bG  = bid % nBG;     bid /= nBG;
    coT = bid;
  }
  int b0  = bG * BPB;

  int tpr = Hout / TILE;
  int ox0 = (spT % tpr) * TILE;
  int oy0 = (spT / tpr) * TILE;
  int co0 = coT * COT;

  int b  = b0 + bl;
  int ix = (ox0 + tx)*S - pad;
  int iy = (oy0 + tyq)*S - pad;

  bool okx[K];
  #pragma unroll
  for (int kx = 0; kx < K; kx++) okx[kx] = (unsigned)(ix + kx) < (unsigned)Hin;
  bool oky[4*K];
  #pragma unroll
  for (int r = 0; r < 4; r++){
    #pragma unroll
    for (int ky = 0; ky < K; ky++)
      oky[r*K + ky] = (unsigned)(iy + r*S + ky) < (unsigned)Hin;
  }

  float acc[COT*4];
  #pragma unroll
  for (int i = 0; i < COT*4; i++) acc[i] = 0.f;

  size_t chs = (size_t)Hin*Hin;
  const float* ipb = in + (size_t)b*Cin*chs + (iy*Hin + ix);

  for (int ci0 = 0; ci0 < Cin; ci0 += CCW){
    if (ci0) __syncthreads();
    #pragma unroll
    for (int it = 0; it < NW; it++){
      int i = tid + it*256;
      if (i < CCW*KK*COT){
        int co = i % COT;
        int r  = i / COT;
        sW[i] = wt[((size_t)(co0+co)*Cin + ci0 + r/KK)*KK + (r % KK)];
      }
    }
    __syncthreads();

    const float* ip = ipb + (size_t)ci0*chs;
    for (int cc = 0; cc < CCW; cc++, ip += chs){
      #pragma unroll
      for (int ky = 0; ky < K; ky++){
        #pragma unroll
        for (int kx = 0; kx < K; kx++){
          const float* rp = ip + ky*Hin + kx;
          float t0 = rp[0];
          float t1 = rp[S*Hin];
          float t2 = rp[2*S*Hin];
          float t3 = rp[3*S*Hin];
          float v0 = (oky[0*K+ky] && okx[kx]) ? t0 : 0.f;
          float v1 = (oky[1*K+ky] && okx[kx]) ? t1 : 0.f;
          float v2 = (oky[2*K+ky] && okx[kx]) ? t2 : 0.f;
          float v3 = (oky[3*K+ky] && okx[kx]) ? t3 : 0.f;
          const float4* wv = (const float4*)&sW[(cc*KK + ky*K + kx)*COT];
          #pragma unroll
          for (int g = 0; g < COT/4; g++){
            float4 w = wv[g];
            acc[(g*4+0)*4+0] += w.x*v0; acc[(g*4+0)*4+1] += w.x*v1;
            acc[(g*4+0)*4+2] += w.x*v2; acc[(g*4+0)*4+3] += w.x*v3;
            acc[(g*4+1)*4+0] += w.y*v0; acc[(g*4+1)*4+1] += w.y*v1;
            acc[(g*4+1)*4+2] += w.y*v2; acc[(g*4+1)*4+3] += w.y*v3;
            acc[(g*4+2)*4+0] += w.z*v0; acc[(g*4+2)*4+1] += w.z*v1;
            acc[(g*4+2)*4+2] += w.z*v2; acc[(g*4+2)*4+3] += w.z*v3;
            acc[(g*4+3)*4+0] += w.w*v0; acc[(g*4+3)*4+1] += w.w*v1;
            acc[(g*4+3)*4+2] += w.w*v2; acc[(g*4+3)*4+3] += w.w*v3;
          }
        }
      }
    }
  }

  #pragma unroll
  for (int co = 0; co < COT; co++){
    size_t base = (((size_t)b*Cout + co0+co)*Hout + oy0 + tyq)*Hout + ox0 + tx;
    #pragma unroll
    for (int r = 0; r < 4; r++){
      float v = acc[co*4 + r];
      if (res) v += res[base + (size_t)r*Hout];
      if (relu) v = fmaxf(v, 0.f);
      out[base + (size_t)r*Hout] = v;
    }
  }
}

// ---------------- pool + transformer ----------------
__global__ void k_pool(const float* __restrict__ in, float* __restrict__ feat, int cnt)
{
  int gid = blockIdx.x*256 + threadIdx.x;
  if (gid >= cnt) return;
  const float* p = in + (size_t)gid*256;
  float s = 0.f;
  for (int i = 0; i < 256; i++) s += p[i];
  feat[gid] = s * (1.f/256.f);
}

__global__ void k_pe(const float* __restrict__ feat, const float* __restrict__ theta,
                     const float* __restrict__ idxin, const float* __restrict__ pos_w,
                     const float* __restrict__ pos_b, float* __restrict__ hs)
{
  int gid = blockIdx.x*256 + threadIdx.x;
  if (gid >= 64*256) return;
  int n = gid >> 8, d = gid & 255;
  float s = pos_b[d];
  #pragma unroll
  for (int j = 0; j < 6; j++) s += theta[n*6+j] * pos_w[j*256+d];
  #pragma unroll
  for (int j = 0; j < 2; j++) s += idxin[n*2+j] * pos_w[(6+j)*256+d];
  hs[gid] = feat[gid] + s;
}

__global__ void k_qkv(const float* __restrict__ hs, const float* __restrict__ wq,
                      const float* __restrict__ wk, const float* __restrict__ wv,
                      float* __restrict__ qkv)
{
  int gid = blockIdx.x*256 + threadIdx.x;
  if (gid >= 64*768) return;
  int n = gid / 768, m = gid % 768;
  int which = m >> 8, j = m & 255;
  const float* w = (which == 0) ? wq : (which == 1) ? wk : wv;
  const float* h = hs + n*256;
  float s = 0.f;
  for (int i = 0; i < 256; i++) s += h[i] * w[i*256 + j];
  qkv[which*16384 + n*256 + j] = s;
}

__global__ void k_attn(const float* __restrict__ qkv, float* __restrict__ aout)
{
  int h = blockIdx.x;
  int tid = threadIdx.x;
  __shared__ float sc[4096];
  const float* q  = qkv + h*64;
  const float* kk = qkv + 16384 + h*64;
  const float* v  = qkv + 32768 + h*64;
  for (int idx = tid; idx < 4096; idx += 256){
    int qi = idx >> 6, ki = idx & 63;
    float s = 0.f;
    for (int d = 0; d < 64; d++) s += q[qi*256+d] * kk[ki*256+d];
    sc[idx] = s * 0.125f;
  }
  __syncthreads();
  if (tid < 64){
    float mx = -1e30f;
    for (int k = 0; k < 64; k++) mx = fmaxf(mx, sc[tid*64+k]);
    float sum = 0.f;
    for (int k = 0; k < 64; k++){ float e = __expf(sc[tid*64+k]-mx); sc[tid*64+k] = e; sum += e; }
    float inv = 1.f/sum;
    for (int k = 0; k < 64; k++) sc[tid*64+k] *= inv;
  }
  __syncthreads();
  for (int idx = tid; idx < 4096; idx += 256){
    int qi = idx >> 6, d = idx & 63;
    float s = 0.f;
    for (int ki = 0; ki < 64; ki++) s += sc[qi*64+ki] * v[ki*256+d];
    aout[qi*256 + h*64 + d] = s;
  }
}

__global__ void k_proj_ln(const float* __restrict__ ain, const float* __restrict__ wo,
                          const float* __restrict__ g, const float* __restrict__ bb,
                          float* __restrict__ hs)
{
  int n = blockIdx.x, d = threadIdx.x;
  __shared__ float row[256];
  __shared__ float red[256];
  __shared__ float smean, svar;
  row[d] = ain[n*256+d];
  __syncthreads();
  float s = hs[n*256+d];
  for (int i = 0; i < 256; i++) s += row[i] * wo[i*256+d];
  red[d] = s; __syncthreads();
  for (int off = 128; off; off >>= 1){ if (d < off) red[d] += red[d+off]; __syncthreads(); }
  if (d == 0) smean = red[0] * (1.f/256.f);
  __syncthreads();
  float c = s - smean;
  red[d] = c*c; __syncthreads();
  for (int off = 128; off; off >>= 1){ if (d < off) red[d] += red[d+off]; __syncthreads(); }
  if (d == 0) svar = red[0] * (1.f/256.f);
  __syncthreads();
  hs[n*256+d] = c * rsqrtf(svar + 1e-5f) * g[d] + bb[d];
}

__global__ void k_ff1(const float* __restrict__ hs, const float* __restrict__ w,
                      const float* __restrict__ b, float* __restrict__ h1)
{
  int gid = blockIdx.x*256 + threadIdx.x;
  if (gid >= 64*512) return;
  int n = gid >> 9, j = gid & 511;
  float s = b[j];
  const float* h = hs + n*256;
  for (int i = 0; i < 256; i++) s += h[i] * w[i*512 + j];
  h1[gid] = fmaxf(s, 0.f);
}

__global__ void k_ff2_ln(const float* __restrict__ h1, const float* __restrict__ w,
                         const float* __restrict__ b, const float* __restrict__ g,
                         const float* __restrict__ bb, float* __restrict__ hs)
{
  int n = blockIdx.x, d = threadIdx.x;
  __shared__ float row[512];
  __shared__ float red[256];
  __shared__ float smean, svar;
  row[d] = h1[n*512+d];
  row[d+256] = h1[n*512+256+d];
  __syncthreads();
  float s = hs[n*256+d] + b[d];
  for (int i = 0; i < 512; i++) s += row[i] * w[i*256+d];
  red[d] = s; __syncthreads();
  for (int off = 128; off; off >>= 1){ if (d < off) red[d] += red[d+off]; __syncthreads(); }
  if (d == 0) smean = red[0] * (1.f/256.f);
  __syncthreads();
  float c = s - smean;
  red[d] = c*c; __syncthreads();
  for (int off = 128; off; off >>= 1){ if (d < off) red[d] += red[d+off]; __syncthreads(); }
  if (d == 0) svar = red[0] * (1.f/256.f);
  __syncthreads();
  hs[n*256+d] = c * rsqrtf(svar + 1e-5f) * g[d] + bb[d];
}

__global__ void k_head(const float* __restrict__ hs, const float* __restrict__ fcw,
                       const float* __restrict__ fcb, float* __restrict__ pvec,
                       float* __restrict__ outx)
{
  int n = threadIdx.x; // 64 threads
  float s = fcb[0];
  const float* h = hs + n*256;
  for (int i = 0; i < 256; i++) s += h[i] * fcw[i];
  __shared__ float xs[64];
  xs[n] = s;
  __syncthreads();
  float mx = -1e30f;
  for (int i = 0; i < 64; i++) mx = fmaxf(mx, xs[i]);
  float sum = 0.f;
  for (int i = 0; i < 64; i++) sum += __expf(xs[i]-mx);
  float val = __expf(s-mx)/sum * 64.f;
  val = fminf(val, 3.f);
  pvec[n] = val;
  outx[n] = val;
}

// ---------------- CG helpers ----------------
__global__ void k_dot(const float* __restrict__ a, const float* __restrict__ b,
                      float* __restrict__ scal, int slot, int n)
{
  int gid = blockIdx.x*blockDim.x + threadIdx.x;
  int stride = gridDim.x*blockDim.x;
  float s = 0.f;
  for (int i = gid; i < n; i += stride) s += a[i]*b[i];
  for (int off = 32; off; off >>= 1) s += __shfl_down(s, off, 64);
  __shared__ float wsum[4];
  int lane = threadIdx.x & 63, wv = threadIdx.x >> 6;
  if (lane == 0) wsum[wv] = s;
  __syncthreads();
  if (threadIdx.x == 0) atomicAdd(&scal[slot], wsum[0]+wsum[1]+wsum[2]+wsum[3]);
}

__global__ void k_rinit(const float* __restrict__ b, const float* __restrict__ A,
                        float* __restrict__ r, float* __restrict__ p)
{
  int gid = blockIdx.x*256 + threadIdx.x;
  if (gid < VN){ float v = b[gid] - A[gid]; r[gid] = v; p[gid] = v; }
}

// x += (scal[sa]/scal[sb]) * p;  r -= alpha * Ap   (div folded in)
__global__ void k_xr(float* __restrict__ x, const float* __restrict__ p,
                     float* __restrict__ r, const float* __restrict__ Ap,
                     const float* __restrict__ scal, int sa, int sb)
{
  int gid = blockIdx.x*256 + threadIdx.x;
  if (gid < VN){
    float a = scal[sa] / scal[sb];
    x[gid] += a * p[gid];
    r[gid] -= a * Ap[gid];
  }
}

__global__ void k_pupd(float* __restrict__ p, const float* __restrict__ r,
                       const float* __restrict__ scal, int sa, int sb)
{
  int gid = blockIdx.x*256 + threadIdx.x;
  if (gid < VN){ float b = scal[sa] / scal[sb]; p[gid] = r[gid] + b * p[gid]; }
}

// final CG step fused with ReLU output: out = max(x + alpha*p, 0)
__global__ void k_xfin(const float* __restrict__ x, const float* __restrict__ p,
                       const float* __restrict__ scal, int sa, int sb,
                       float* __restrict__ out)
{
  int gid = blockIdx.x*256 + threadIdx.x;
  if (gid < VN) out[gid] = fmaxf(x[gid] + (scal[sa] / scal[sb]) * p[gid], 0.f);
}

// ---------------- host launch ----------------
extern "C" void kernel_launch(void* const* d_in, const int* in_sizes, int n_in,
                              void* d_out, int out_size, void* d_ws, size_t ws_size,
                              hipStream_t stream)
{
  const float* theta      = (const float*)d_in[0];
  const float* transforms = (const float*)d_in[1];
  const float* slices     = (const float*)d_in[2];
  const float* volume     = (const float*)d_in[3];
  const float* psf        = (const float*)d_in[4];
  const float* idxv       = (const float*)d_in[5];

  char* wsp = (char*)d_ws;
  auto carve = [&](size_t bytes)->void*{
    void* r = (void*)wsp; wsp += (bytes + 255) & ~(size_t)255; return r;
  };
  float* scal = (float*)carve(16*4);
  float* Rm   = (float*)carve(768*4);
  float* pw   = (float*)carve(32*4);
  float* pvec = (float*)carve(64*4);
  float* feat = (float*)carve(16384*4);
  float* hs   = (float*)carve(16384*4);
  float* qkv  = (float*)carve(49152*4);
  float* aout = (float*)carve(16384*4);
  float* h1   = (float*)carve(32768*4);
  float* mask = (float*)carve((size_t)NSL*NPX*4);
  float* volA = (float*)carve((size_t)VN*4);

  size_t used  = (size_t)(wsp - (char*)d_ws);
  size_t avail = (ws_size > used) ? ws_size - used : 0;
  // CG usage in U: r,p,Ap,b vols + sscr + bval + pcor/G
  size_t cgU   = ((size_t)4*VN + 2*(size_t)NSL*NPX + (size_t)PCN)*4;
  auto needU = [&](int cb)->size_t{
    size_t u = ((size_t)VN + 3*(size_t)cb*262144)*4;
    return (u > cgU) ? u : cgU;
  };
  int CB = 8;
  if (avail >= needU(64) + 4096) CB = 64;
  else if (avail >= needU(32) + 4096) CB = 32;

  size_t cbe = (size_t)CB*262144;
  float* U    = (float*)carve(needU(CB));
  float* z    = U;
  float* bufA = U + VN;
  float* bufB = bufA + cbe;
  float* bufC = bufB + cbe;
  float* bvol = U;
  float* rvol = U + VN;
  float* pvol = U + 2*(size_t)VN;
  float* Avol = U + 3*(size_t)VN;
  float* sscr = U + 4*(size_t)VN;
  float* bval = sscr + (size_t)NSL*NPX;
  float* pcor = bval + (size_t)NSL*NPX;   // shared slot: G during forward, pcor during adjoint

  const int PCB = PCN/256;  // exact

  hipMemsetAsync(scal, 0, 64, stream);
  k_prep<<<1, 64, 0, stream>>>(transforms, psf, Rm, pw);
  k_mask<<<4096, 256, 0, stream>>>(slices, mask);
  k_volcopy<<<8192, 256, 0, stream>>>(volume, volA);
  // prologue A(x0)*mask via lattice-factored forward (G in pcor slot; convs
  // will clobber that slot later, after gcorr has consumed it)
  k_gvol<<<PCB, 256, 0, stream>>>(volA, Rm, pcor);
  k_gcorr<<<4096, 256, 0, stream>>>(pcor, pw, mask, nullptr, z, 2*NPX, NPX);
  k_copy0<<<4096, 256, 0, stream>>>(slices, z);

  const float* w6  = (const float*)d_in[6];
  const float* w7  = (const float*)d_in[7];
  const float* w8  = (const float*)d_in[8];
  const float* w9  = (const float*)d_in[9];
  const float* w10 = (const float*)d_in[10];
  const float* w11 = (const float*)d_in[11];
  const float* w12 = (const float*)d_in[12];
  const float* w13 = (const float*)d_in[13];
  const float* w14 = (const float*)d_in[14];

  for (int c = 0; c < 64/CB; c++){
    const float* zc = z + (size_t)c*CB*2*NPX;
    k_convt<7,2,32,2,16><<<CB*16, 256, 0, stream>>>(zc,  w6,  nullptr, bufA, 2,  128, 64,  64, 2, 1, CB, 4);
    k_convd<3,1,32,16,16><<<CB*16, 256, 0, stream>>>(bufA, w7,  nullptr, bufB, 64, 64,  64,  64, 1, 1, CB, 4, 1);
    k_convd<3,1,32,16,16><<<CB*16, 256, 0, stream>>>(bufB, w8,  bufA,    bufC, 64, 64,  64,  64, 1, 1, CB, 4, 1);
    k_convd<3,2,32,16,16><<<CB*8,  256, 0, stream>>>(bufC, w9,  nullptr, bufA, 64, 64,  128, 32, 0, 1, CB, 1, 0);
    k_convd<1,2,32,16,64><<<CB*8,  256, 0, stream>>>(bufC, w11, nullptr, bufB, 64, 64,  128, 32, 0, 0, CB, 1, 0);
    k_convd<3,1,32,16,16><<<CB*8,  256, 0, stream>>>(bufA, w10, bufB,    bufC, 128,32,  128, 32, 1, 1, CB, 1, 0);
    k_convd<3,2,16,8,32><<<(CB/4)*32, 256, 0, stream>>>(bufC, w12, nullptr, bufA, 128, 32, 256, 16, 0, 1, CB/4, 1, 0);
    k_convd<1,2,16,8,128><<<(CB/4)*32, 256, 0, stream>>>(bufC, w14, nullptr, bufB, 128, 32, 256, 16, 0, 0, CB/4, 1, 0);
    k_convd<3,1,16,8,32><<<(CB/4)*32, 256, 0, stream>>>(bufA, w13, bufB,    bufC, 256, 16, 256, 16, 1, 1, CB/4, 1, 0);
    k_pool<<<CB, 256, 0, stream>>>(bufC, feat + (size_t)c*CB*256, CB*256);
  }

  k_pe<<<64, 256, 0, stream>>>(feat, theta, idxv, (const float*)d_in[15], (const float*)d_in[16], hs);
  for (int l = 0; l < 4; l++){
    k_qkv<<<192, 256, 0, stream>>>(hs, (const float*)d_in[17] + (size_t)l*65536,
                                       (const float*)d_in[18] + (size_t)l*65536,
                                       (const float*)d_in[19] + (size_t)l*65536, qkv);
    k_attn<<<4, 256, 0, stream>>>(qkv, aout);
    k_proj_ln<<<64, 256, 0, stream>>>(aout, (const float*)d_in[20] + (size_t)l*65536,
                                      (const float*)d_in[21] + l*256, (const float*)d_in[22] + l*256, hs);
    k_ff1<<<128, 256, 0, stream>>>(hs, (const float*)d_in[23] + (size_t)l*131072,
                                   (const float*)d_in[24] + l*512, h1);
    k_ff2_ln<<<64, 256, 0, stream>>>(h1, (const float*)d_in[25] + (size_t)l*131072,
                                     (const float*)d_in[26] + l*256, (const float*)d_in[27] + l*256,
                                     (const float*)d_in[28] + l*256, hs);
  }
  k_head<<<1, 64, 0, stream>>>(hs, (const float*)d_in[29], (const float*)d_in[30], pvec,
                               (float*)d_out + VN);

  // ---- CG ----
  k_zscale<<<4096, 256, 0, stream>>>(z, pvec, sscr);
  k_premul<<<4096, 256, 0, stream>>>(slices, mask, pvec, bval);
  k_pcorr<<<PCB, 256, 0, stream>>>(bval, pw, pcor);
  k_sadj<<<8192, 256, 0, stream>>>(pcor, Rm, bvol);                 // b = At(slices*p)
  k_pcorr<<<PCB, 256, 0, stream>>>(sscr, pw, pcor);
  k_sadj<<<8192, 256, 0, stream>>>(pcor, Rm, Avol);                 // AtA(x0)
  k_rinit<<<8192, 256, 0, stream>>>(bvol, Avol, rvol, pvol);
  k_dot<<<512, 256, 0, stream>>>(rvol, rvol, scal, 0, VN);          // rr0
  // iter 1
  k_gvol<<<PCB, 256, 0, stream>>>(pvol, Rm, pcor);                  // G(p)
  k_gcorr<<<4096, 256, 0, stream>>>(pcor, pw, mask, pvec, sscr, NPX, 0);
  k_pcorr<<<PCB, 256, 0, stream>>>(sscr, pw, pcor);                 // overwrites G (safe)
  k_sadj<<<8192, 256, 0, stream>>>(pcor, Rm, Avol);
  k_dot<<<512, 256, 0, stream>>>(pvol, Avol, scal, 1, VN);          // pAp1
  k_xr<<<8192, 256, 0, stream>>>(volA, pvol, rvol, Avol, scal, 0, 1);
  k_dot<<<512, 256, 0, stream>>>(rvol, rvol, scal, 3, VN);          // rr1
  k_pupd<<<8192, 256, 0, stream>>>(pvol, rvol, scal, 3, 0);         // beta = rr1/rr0
  // iter 2
  k_gvol<<<PCB, 256, 0, stream>>>(pvol, Rm, pcor);
  k_gcorr<<<4096, 256, 0, stream>>>(pcor, pw, mask, pvec, sscr, NPX, 0);
  k_pcorr<<<PCB, 256, 0, stream>>>(sscr, pw, pcor);
  k_sadj<<<8192, 256, 0, stream>>>(pcor, Rm, Avol);
  k_dot<<<512, 256, 0, stream>>>(pvol, Avol, scal, 5, VN);          // pAp2
  k_xfin<<<8192, 256, 0, stream>>>(volA, pvol, scal, 3, 5, (float*)d_out);
}

// Round 15
// 4442.427 us; speedup vs baseline: 3.9211x; 3.9211x over previous
//
#include <hip/hip_runtime.h>
#include <hip/hip_bf16.h>

#define NSL 64
#define NPX 16384   // 128*128
#define VN  2097152 // 128^3
#define PCL 16900   // 130*130 lattice layer
#define PCS 50700   // 3*PCL per slice
#define PCN 3244800 // NSL*PCS

// ---------------- prep: per-slice R,t (fp32 inputs) ----------------
__global__ void k_prep(const float* __restrict__ tr, const float* __restrict__ psf,
                       float* __restrict__ Rm, float* __restrict__ pw)
{
  int n = threadIdx.x;
  if (n < 27) pw[n] = psf[n];
  if (n >= NSL) return;
  #pragma unroll
  for (int i = 0; i < 3; i++){
    #pragma unroll
    for (int j = 0; j < 3; j++) Rm[n*12 + i*3 + j] = tr[n*12 + i*4 + j];
    Rm[n*12 + 9 + i] = tr[n*12 + i*4 + 3];
  }
}

// ---------------- mask ----------------
__global__ void k_mask(const float* __restrict__ slices, float* __restrict__ mask)
{
  int gid = blockIdx.x*256 + threadIdx.x;
  if (gid >= NSL*NPX) return;
  int n = gid >> 14, p = gid & 16383;
  int py = p >> 7, px = p & 127;
  const float* s = slices + n*NPX;
  bool any = false;
  for (int dy = -1; dy <= 1; dy++){
    int yy = py + dy;
    if ((unsigned)yy >= 128u) continue;
    for (int dx = -1; dx <= 1; dx++){
      int xx = px + dx;
      if ((unsigned)xx >= 128u) continue;
      any = any || (s[yy*128 + xx] > 0.f);
    }
  }
  mask[gid] = any ? 1.f : 0.f;
}

__global__ void k_volcopy(const float* __restrict__ v, float* __restrict__ o)
{
  int gid = blockIdx.x*256 + threadIdx.x;
  if (gid < VN) o[gid] = v[gid];
}

__global__ void k_copy0(const float* __restrict__ slices, float* __restrict__ z)
{
  int gid = blockIdx.x*256 + threadIdx.x;
  if (gid >= NSL*NPX) return;
  int n = gid >> 14, p = gid & 16383;
  z[n*2*NPX + p] = slices[gid];
}

// premultiply slice values by mask (and optional per-slice scale)
__global__ void k_premul(const float* __restrict__ s, const float* __restrict__ mask,
                         const float* __restrict__ ps, float* __restrict__ o)
{
  int gid = blockIdx.x*256 + threadIdx.x;
  if (gid >= NSL*NPX) return;
  float v = s[gid] * mask[gid];
  if (ps) v *= ps[gid >> 14];
  o[gid] = v;
}

// sscr[n][p] = z2[n][p] * ps[n]  (reuse prologue A(x0)*mask, which survives convs)
__global__ void k_zscale(const float* __restrict__ z, const float* __restrict__ ps,
                         float* __restrict__ out)
{
  int gid = blockIdx.x*256 + threadIdx.x;
  if (gid >= NSL*NPX) return;
  int n = gid >> 14, p = gid & 16383;
  out[gid] = z[n*2*NPX + NPX + p] * ps[n];
}

// ---------------- trilinear gather helper ----------------
__device__ __forceinline__ float lerpf(float a, float b, float t){ return fmaf(t, b-a, a); }

__device__ __forceinline__ float tri_gather(const float* __restrict__ vol, float x, float y, float z)
{
  float xf = floorf(x), yf = floorf(y), zf = floorf(z);
  int x0 = (int)xf, y0 = (int)yf, z0 = (int)zf;
  float fx = x - xf, fy = y - yf, fz = z - zf;
  if ((unsigned)x0 < 127u && (unsigned)y0 < 127u && (unsigned)z0 < 127u){
    const float* p = vol + (z0*128 + y0)*128 + x0;
    float c00 = lerpf(p[0],     p[1],     fx);
    float c01 = lerpf(p[128],   p[129],   fx);
    float c10 = lerpf(p[16384], p[16385], fx);
    float c11 = lerpf(p[16512], p[16513], fx);
    return lerpf(lerpf(c00, c01, fy), lerpf(c10, c11, fy), fz);
  }
  float gx0 = 1.f - fx, gy0 = 1.f - fy, gz0 = 1.f - fz;
  bool vx0 = (unsigned)x0 < 128u, vx1 = (unsigned)(x0+1) < 128u;
  bool vy0 = (unsigned)y0 < 128u, vy1 = (unsigned)(y0+1) < 128u;
  bool vz0 = (unsigned)z0 < 128u, vz1 = (unsigned)(z0+1) < 128u;
  int i0 = (z0*128 + y0)*128 + x0;
  float acc = 0.f;
  if (vz0){
    if (vy0){
      if (vx0) acc += gx0*gy0*gz0 * vol[i0];
      if (vx1) acc += fx *gy0*gz0 * vol[i0+1];
    }
    if (vy1){
      if (vx0) acc += gx0*fy*gz0 * vol[i0+128];
      if (vx1) acc += fx *fy*gz0 * vol[i0+129];
    }
  }
  if (vz1){
    int i1 = i0 + 16384;
    if (vy0){
      if (vx0) acc += gx0*gy0*fz * vol[i1];
      if (vx1) acc += fx *gy0*fz * vol[i1+1];
    }
    if (vy1){
      if (vx0) acc += gx0*fy*fz * vol[i1+128];
      if (vx1) acc += fx *fy*fz * vol[i1+129];
    }
  }
  return acc;
}

// ---------------- A (forward), lattice-factored ----------------
__global__ void k_gvol(const float* __restrict__ vol, const float* __restrict__ Rm,
                       float* __restrict__ out)
{
  int gid = blockIdx.x*256 + threadIdx.x;
  if (gid >= PCN) return;
  int n = gid / PCS;
  int r = gid % PCS;
  int w = r / PCL - 1;
  int q = r % PCL;
  int v = q / 130 - 1, u = q % 130 - 1;
  const float* R = Rm + n*12;
  float fu = (float)u - 63.5f, fv = (float)v - 63.5f, fw = (float)w;
  float x = R[0]*fu + R[1]*fv + R[2]*fw + R[9]  + 63.5f;
  float y = R[3]*fu + R[4]*fv + R[5]*fw + R[10] + 63.5f;
  float z = R[6]*fu + R[7]*fv + R[8]*fw + R[11] + 63.5f;
  out[gid] = tri_gather(vol, x, y, z);
}

__global__ void k_gcorr(const float* __restrict__ G, const float* __restrict__ pw,
                        const float* __restrict__ mask, const float* __restrict__ ps,
                        float* __restrict__ out, int outStride, int outOff)
{
  __shared__ float spw[27];
  if (threadIdx.x < 27) spw[threadIdx.x] = pw[threadIdx.x];
  __syncthreads();
  int gid = blockIdx.x*256 + threadIdx.x;   // exactly NSL*NPX threads
  int n = gid >> 14;
  int p = gid & 16383;
  int py = p >> 7, px = p & 127;
  const float* Gn = G + n*PCS;
  float acc = 0.f;
  #pragma unroll
  for (int k = 0; k < 27; k++){
    int ox = k % 3, oy = (k/3) % 3, oz = k/9;   // == offset+1
    acc += spw[k] * Gn[oz*PCL + (py+oy)*130 + (px+ox)];
  }
  float val = acc * mask[gid];
  if (ps) val *= ps[n];
  out[n*outStride + outOff + p] = val;
}

// ---------------- PSF pre-correlation for the adjoint ----------------
__global__ void k_pcorr(const float* __restrict__ val, const float* __restrict__ pw,
                        float* __restrict__ out)
{
  int gid = blockIdx.x*256 + threadIdx.x;
  if (gid >= PCN) return;
  int n = gid / PCS;
  int r = gid % PCS;
  int l = r / PCL;
  int q = r % PCL;
  int my = q / 130 - 1, mx = q % 130 - 1;
  const float* vs = val + n*NPX;
  const float* pg = pw + l*9;
  float inner = 0.f;
  #pragma unroll
  for (int oy = -1; oy <= 1; oy++){
    int qy = my - oy;
    if ((unsigned)qy >= 128u) continue;
    const float* vrow = vs + qy*128;
    const float* pr = pg + (oy+1)*3;
    #pragma unroll
    for (int ox = -1; ox <= 1; ox++){
      int qx = mx - ox;
      if ((unsigned)qx >= 128u) continue;
      inner += pr[ox+1] * vrow[qx];
    }
  }
  out[gid] = inner;
}

// ---------------- At: adjoint in GATHER form (atomic-free) ----------------
__global__ __launch_bounds__(256, 4) void k_sadj(
    const float* __restrict__ pcor,  // [NSL][3][130][130]
    const float* __restrict__ Rm,    // [NSL][12]
    float* __restrict__ out)         // [VN], overwritten
{
  __shared__ float sR[NSL*12];
  __shared__ int   slist[NSL];
  __shared__ int   scnt;
  int tid = threadIdx.x;
  for (int i = tid; i < NSL*12; i += 256) sR[i] = Rm[i];
  __syncthreads();

  int b  = blockIdx.x;
  int bx = (b & 15) * 8;
  int by = ((b >> 4) & 15) * 8;
  int bz = (b >> 8) * 4;

  if (tid < 64){
    const float* R = &sR[tid*12];
    float axc = ((float)bx + 3.5f) - 63.5f - R[9];
    float ayc = ((float)by + 3.5f) - 63.5f - R[10];
    float azc = ((float)bz + 1.5f) - 63.5f - R[11];
    float Zc = R[2]*axc + R[5]*ayc + R[8]*azc;
    float rZ = fabsf(R[2])*3.5f + fabsf(R[5])*3.5f + fabsf(R[8])*1.5f;
    bool ok = fabsf(Zc) < 2.7321f + rZ;
    if (ok){
      float Pc = R[0]*axc + R[3]*ayc + R[6]*azc + 63.5f;
      float rP = fabsf(R[0])*3.5f + fabsf(R[3])*3.5f + fabsf(R[6])*1.5f;
      float Qc = R[1]*axc + R[4]*ayc + R[7]*azc + 63.5f;
      float rQ = fabsf(R[1])*3.5f + fabsf(R[4])*3.5f + fabsf(R[7])*1.5f;
      ok = (Pc + rP > -2.7321f) && (Pc - rP < 130.7321f)
        && (Qc + rQ > -2.7321f) && (Qc - rQ < 130.7321f);
    }
    unsigned long long m = __ballot(ok);
    if (ok) slist[__popcll(m & ((1ull << tid) - 1ull))] = tid;
    if (tid == 0) scnt = (int)__popcll(m);
  }
  __syncthreads();
  int cnt = scnt;

  int lx = tid & 7, ly = (tid >> 3) & 7, lz = tid >> 6;
  int vx = bx + lx, vy = by + ly, vz = bz + lz;

  float cvx = (float)vx - 63.5f;
  float cvy = (float)vy - 63.5f;
  float cvz = (float)vz - 63.5f;

  float acc = 0.f;
  for (int i = 0; i < cnt; i++){
    int n = slist[i];
    const float* R = &sR[n*12];
    float ax = cvx - R[9], ay = cvy - R[10], az = cvz - R[11]; // v - t - ctr
    float Z = R[2]*ax + R[5]*ay + R[8]*az;
    if (fabsf(Z) >= 2.7321f) continue;
    float P = R[0]*ax + R[3]*ay + R[6]*az + 63.5f;
    float Q = R[1]*ax + R[4]*ay + R[7]*az + 63.5f;
    if (P <= -2.7321f || P >= 130.7321f || Q <= -2.7321f || Q >= 130.7321f) continue;
    const float* pc = pcor + n*PCS;

    #pragma unroll
    for (int mz = -1; mz <= 1; mz++){
      float dz = (float)mz - Z;
      float rem2 = 3.f - dz*dz;
      if (rem2 <= 0.f) continue;
      float sy = sqrtf(rem2);
      int my0 = (int)ceilf(Q - sy), my1 = (int)floorf(Q + sy);
      if (my0 < -1) my0 = -1;
      if (my1 > 128) my1 = 128;
      const float* pl = pc + (mz+1)*PCL;
      for (int my = my0; my <= my1; my++){
        float dy = (float)my - Q;
        float rem1 = rem2 - dy*dy;
        if (rem1 <= 0.f) continue;
        float sx = sqrtf(rem1);
        int mx0 = (int)ceilf(P - sx), mx1 = (int)floorf(P + sx);
        if (mx0 < -1) mx0 = -1;
        if (mx1 > 128) mx1 = 128;
        float dx = (float)mx0 - P;
        float rx = R[0]*dx + R[1]*dy + R[2]*dz;
        float ry = R[3]*dx + R[4]*dy + R[5]*dz;
        float rz = R[6]*dx + R[7]*dy + R[8]*dz;
        const float* crow = pl + (my+1)*130 + (mx0+1);
        for (int mx = mx0; mx <= mx1; mx++){
          float w3 = fmaxf(1.f - fabsf(rx), 0.f)
                   * fmaxf(1.f - fabsf(ry), 0.f)
                   * fmaxf(1.f - fabsf(rz), 0.f);
          if (w3 > 0.f) acc += w3 * crow[mx - mx0];
          rx += R[0]; ry += R[3]; rz += R[6];
        }
      }
    }
  }
  out[(vz*128 + vy)*128 + vx] = acc;
}

// ---------------- tiled conv (LDS-staged input) — used only for conv1 (Cin=2) ----
template<int K, int S, int TILE, int CC, int COT>
__global__ __launch_bounds__(256, 2) void k_convt(
    const float* __restrict__ in, const float* __restrict__ wt,
    const float* __restrict__ res, float* __restrict__ out,
    int Cin, int Hin, int Cout, int Hout,
    int pad, int relu, int nBG, int spTiles)
{
  constexpr int BPB  = 1024 / (TILE*TILE);
  constexpr int ITX  = (K==1) ? TILE : (TILE-1)*S + K;
  constexpr int ITP  = ITX | 1;
  constexpr int KK   = K*K;
  constexpr int PERB = TILE*TILE/4;
  constexpr int RS   = (K==1) ? 1 : S;
  constexpr int NIN  = (CC*ITX*ITX + PERB - 1)/PERB;
  constexpr int NWT  = (COT*CC*KK + 255)/256;

  __shared__ float sIn[BPB*CC*ITX*ITP];
  __shared__ float sW[CC*KK*COT];

  int tid = threadIdx.x;
  int bl  = tid / PERB;
  int t2  = tid % PERB;
  int tx  = t2 % TILE;
  int tyq = (t2 / TILE) * 4;

  int bid = blockIdx.x;
  int spT = bid % spTiles; bid /= spTiles;
  int bG  = bid % nBG;     bid /= nBG;
  int coT = bid;
  int b0  = bG * BPB;

  int tpr = Hout / TILE;
  int ox0 = (spT % tpr) * TILE;
  int oy0 = (spT / tpr) * TILE;
  int co0 = coT * COT;
  int ix0 = ox0*S - pad;
  int iy0 = oy0*S - pad;

  float acc[COT*4];
  #pragma unroll
  for (int i = 0; i < COT*4; i++) acc[i] = 0.f;

  for (int ci0 = 0; ci0 < Cin; ci0 += CC){
    #pragma unroll
    for (int it = 0; it < NWT; it++){
      int i = tid + it*256;
      if (i < COT*CC*KK){
        int co = i / (CC*KK);
        int r  = i % (CC*KK);
        sW[r*COT + co] = wt[((size_t)(co0+co)*Cin + ci0 + r/KK)*KK + (r % KK)];
      }
    }
    #pragma unroll
    for (int it = 0; it < NIN; it++){
      int i = t2 + it*PERB;
      if (i < CC*ITX*ITX){
        int cc = i / (ITX*ITX);
        int r  = i % (ITX*ITX);
        int yy = r / ITX, xx = r % ITX;
        int gy = (K==1) ? iy0 + yy*S : iy0 + yy;
        int gx = (K==1) ? ix0 + xx*S : ix0 + xx;
        float v = 0.f;
        if ((unsigned)gy < (unsigned)Hin && (unsigned)gx < (unsigned)Hin)
          v = in[(((size_t)(b0+bl)*Cin + ci0+cc)*Hin + gy)*Hin + gx];
        sIn[((bl*CC + cc)*ITX + yy)*ITP + xx] = v;
      }
    }
    __syncthreads();

    #pragma unroll
    for (int cc = 0; cc < CC; cc++){
      const float* ip = &sIn[(bl*CC + cc)*ITX*ITP];
      #pragma unroll
      for (int ky = 0; ky < K; ky++){
        #pragma unroll
        for (int kx = 0; kx < K; kx++){
          int xi = (K==1) ? tx : tx*S + kx;
          int yb = (K==1) ? tyq : tyq*S + ky;
          float v0 = ip[(yb       )*ITP + xi];
          float v1 = ip[(yb +   RS)*ITP + xi];
          float v2 = ip[(yb + 2*RS)*ITP + xi];
          float v3 = ip[(yb + 3*RS)*ITP + xi];
          const float4* wv = (const float4*)&sW[(cc*KK + ky*K + kx)*COT];
          #pragma unroll
          for (int g = 0; g < COT/4; g++){
            float4 w = wv[g];
            acc[(g*4+0)*4+0] += w.x*v0; acc[(g*4+0)*4+1] += w.x*v1;
            acc[(g*4+0)*4+2] += w.x*v2; acc[(g*4+0)*4+3] += w.x*v3;
            acc[(g*4+1)*4+0] += w.y*v0; acc[(g*4+1)*4+1] += w.y*v1;
            acc[(g*4+1)*4+2] += w.y*v2; acc[(g*4+1)*4+3] += w.y*v3;
            acc[(g*4+2)*4+0] += w.z*v0; acc[(g*4+2)*4+1] += w.z*v1;
            acc[(g*4+2)*4+2] += w.z*v2; acc[(g*4+2)*4+3] += w.z*v3;
            acc[(g*4+3)*4+0] += w.w*v0; acc[(g*4+3)*4+1] += w.w*v1;
            acc[(g*4+3)*4+2] += w.w*v2; acc[(g*4+3)*4+3] += w.w*v3;
          }
        }
      }
    }
    __syncthreads();
  }

  int b = b0 + bl;
  #pragma unroll
  for (int co = 0; co < COT; co++){
    size_t base = (((size_t)b*Cout + co0+co)*Hout + oy0 + tyq)*Hout + ox0 + tx;
    #pragma unroll
    for (int r = 0; r < 4; r++){
      float v = acc[co*4 + r];
      if (res) v += res[base + (size_t)r*Hout];
      if (relu) v = fmaxf(v, 0.f);
      out[base + (size_t)r*Hout] = v;
    }
  }
}

// ---------------- direct conv (input from L1/L2, weights-only LDS) ----------------
// R6 proven inner loop: inline per-tap loads pipeline under FMAs.
// FINAL CONFIG — conv param space exhaustively probed; do not modify:
//  - launch_bounds (256,2): (256,4) forces VGPR->64, acc spills, 5x (R13)
//  - COT=16/grid-512: COT=32 spills (R8); COT halved doubles overhead (R12)
//  - no register strip reuse (R7: WAR hazard, -16%)
//  - residency cap ~8 waves/CU is structural (R12/R13: unchanged at VGPR 64)
// swz: XCD-aware bijective block swizzle (R10: FETCH -28%, timing-neutral).
template<int K, int S, int TILE, int COT, int CCW>
__global__ __launch_bounds__(256, 2) void k_convd(
    const float* __restrict__ in, const float* __restrict__ wt,
    const float* __restrict__ res, float* __restrict__ out,
    int Cin, int Hin, int Cout, int Hout,
    int pad, int relu, int nBG, int spTiles, int swz)
{
  constexpr int PERB = TILE*TILE/4;
  constexpr int BPB  = 1024 / (TILE*TILE);
  constexpr int KK   = K*K;
  constexpr int NW   = (CCW*KK*COT + 255)/256;

  __shared__ float sW[CCW*KK*COT];

  int tid = threadIdx.x;
  int bl  = tid / PERB;
  int t2  = tid % PERB;
  int tx  = t2 % TILE;
  int tyq = (t2 / TILE) * 4;

  int bid = blockIdx.x;
  int spT, bG, coT;
  if (swz){
    int nCo = Cout / COT;
    int u = bid & 7; bid >>= 3;
    coT = bid % nCo; bid /= nCo;
    int tile = bid * 8 + u;        // [0, spTiles*nBG)
    spT = tile % spTiles;
    bG  = tile / spTiles;
  } else {
    spT = bid % spTiles; bid /= spTiles;
    bG  = bid % nBG;     bid /= nBG;
    coT = bid;
  }
  int b0  = bG * BPB;

  int tpr = Hout / TILE;
  int ox0 = (spT % tpr) * TILE;
  int oy0 = (spT / tpr) * TILE;
  int co0 = coT * COT;

  int b  = b0 + bl;
  int ix = (ox0 + tx)*S - pad;
  int iy = (oy0 + tyq)*S - pad;

  bool okx[K];
  #pragma unroll
  for (int kx = 0; kx < K; kx++) okx[kx] = (unsigned)(ix + kx) < (unsigned)Hin;
  bool oky[4*K];
  #pragma unroll
  for (int r = 0; r < 4; r++){
    #pragma unroll
    for (int ky = 0; ky < K; ky++)
      oky[r*K + ky] = (unsigned)(iy + r*S + ky) < (unsigned)Hin;
  }

  float acc[COT*4];
  #pragma unroll
  for (int i = 0; i < COT*4; i++) acc[i] = 0.f;

  size_t chs = (size_t)Hin*Hin;
  const float* ipb = in + (size_t)b*Cin*chs + (iy*Hin + ix);

  for (int ci0 = 0; ci0 < Cin; ci0 += CCW){
    if (ci0) __syncthreads();
    #pragma unroll
    for (int it = 0; it < NW; it++){
      int i = tid + it*256;
      if (i < CCW*KK*COT){
        int co = i % COT;
        int r  = i / COT;
        sW[i] = wt[((size_t)(co0+co)*Cin + ci0 + r/KK)*KK + (r % KK)];
      }
    }
    __syncthreads();

    const float* ip = ipb + (size_t)ci0*chs;
    for (int cc = 0; cc < CCW; cc++, ip += chs){
      #pragma unroll
      for (int ky = 0; ky < K; ky++){
        #pragma unroll
        for (int kx = 0; kx < K; kx++){
          const float* rp = ip + ky*Hin + kx;
          float t0 = rp[0];
          float t1 = rp[S*Hin];
          float t2 = rp[2*S*Hin];
          float t3 = rp[3*S*Hin];
          float v0 = (oky[0*K+ky] && okx[kx]) ? t0 : 0.f;
          float v1 = (oky[1*K+ky] && okx[kx]) ? t1 : 0.f;
          float v2 = (oky[2*K+ky] && okx[kx]) ? t2 : 0.f;
          float v3 = (oky[3*K+ky] && okx[kx]) ? t3 : 0.f;
          const float4* wv = (const float4*)&sW[(cc*KK + ky*K + kx)*COT];
          #pragma unroll
          for (int g = 0; g < COT/4; g++){
            float4 w = wv[g];
            acc[(g*4+0)*4+0] += w.x*v0; acc[(g*4+0)*4+1] += w.x*v1;
            acc[(g*4+0)*4+2] += w.x*v2; acc[(g*4+0)*4+3] += w.x*v3;
            acc[(g*4+1)*4+0] += w.y*v0; acc[(g*4+1)*4+1] += w.y*v1;
            acc[(g*4+1)*4+2] += w.y*v2; acc[(g*4+1)*4+3] += w.y*v3;
            acc[(g*4+2)*4+0] += w.z*v0; acc[(g*4+2)*4+1] += w.z*v1;
            acc[(g*4+2)*4+2] += w.z*v2; acc[(g*4+2)*4+3] += w.z*v3;
            acc[(g*4+3)*4+0] += w.w*v0; acc[(g*4+3)*4+1] += w.w*v1;
            acc[(g*4+3)*4+2] += w.w*v2; acc[(g*4+3)*4+3] += w.w*v3;
          }
        }
      }
    }
  }

  #pragma unroll
  for (int co = 0; co < COT; co++){
    size_t base = (((size_t)b*Cout + co0+co)*Hout + oy0 + tyq)*Hout + ox0 + tx;
    #pragma unroll
    for (int r = 0; r < 4; r++){
      float v = acc[co*4 + r];
      if (res) v += res[base + (size_t)r*Hout];
      if (relu) v = fmaxf(v, 0.f);
      out[base + (size_t)r*Hout] = v;
    }
  }
}

// ---------------- pool + transformer ----------------
__global__ void k_pool(const float* __restrict__ in, float* __restrict__ feat, int cnt)
{
  int gid = blockIdx.x*256 + threadIdx.x;
  if (gid >= cnt) return;
  const float* p = in + (size_t)gid*256;
  float s = 0.f;
  for (int i = 0; i < 256; i++) s += p[i];
  feat[gid] = s * (1.f/256.f);
}

__global__ void k_pe(const float* __restrict__ feat, const float* __restrict__ theta,
                     const float* __restrict__ idxin, const float* __restrict__ pos_w,
                     const float* __restrict__ pos_b, float* __restrict__ hs)
{
  int gid = blockIdx.x*256 + threadIdx.x;
  if (gid >= 64*256) return;
  int n = gid >> 8, d = gid & 255;
  float s = pos_b[d];
  #pragma unroll
  for (int j = 0; j < 6; j++) s += theta[n*6+j] * pos_w[j*256+d];
  #pragma unroll
  for (int j = 0; j < 2; j++) s += idxin[n*2+j] * pos_w[(6+j)*256+d];
  hs[gid] = feat[gid] + s;
}

__global__ void k_qkv(const float* __restrict__ hs, const float* __restrict__ wq,
                      const float* __restrict__ wk, const float* __restrict__ wv,
                      float* __restrict__ qkv)
{
  int gid = blockIdx.x*256 + threadIdx.x;
  if (gid >= 64*768) return;
  int n = gid / 768, m = gid % 768;
  int which = m >> 8, j = m & 255;
  const float* w = (which == 0) ? wq : (which == 1) ? wk : wv;
  const float* h = hs + n*256;
  float s = 0.f;
  for (int i = 0; i < 256; i++) s += h[i] * w[i*256 + j];
  qkv[which*16384 + n*256 + j] = s;
}

__global__ void k_attn(const float* __restrict__ qkv, float* __restrict__ aout)
{
  int h = blockIdx.x;
  int tid = threadIdx.x;
  __shared__ float sc[4096];
  const float* q  = qkv + h*64;
  const float* kk = qkv + 16384 + h*64;
  const float* v  = qkv + 32768 + h*64;
  for (int idx = tid; idx < 4096; idx += 256){
    int qi = idx >> 6, ki = idx & 63;
    float s = 0.f;
    for (int d = 0; d < 64; d++) s += q[qi*256+d] * kk[ki*256+d];
    sc[idx] = s * 0.125f;
  }
  __syncthreads();
  if (tid < 64){
    float mx = -1e30f;
    for (int k = 0; k < 64; k++) mx = fmaxf(mx, sc[tid*64+k]);
    float sum = 0.f;
    for (int k = 0; k < 64; k++){ float e = __expf(sc[tid*64+k]-mx); sc[tid*64+k] = e; sum += e; }
    float inv = 1.f/sum;
    for (int k = 0; k < 64; k++) sc[tid*64+k] *= inv;
  }
  __syncthreads();
  for (int idx = tid; idx < 4096; idx += 256){
    int qi = idx >> 6, d = idx & 63;
    float s = 0.f;
    for (int ki = 0; ki < 64; ki++) s += sc[qi*64+ki] * v[ki*256+d];
    aout[qi*256 + h*64 + d] = s;
  }
}

__global__ void k_proj_ln(const float* __restrict__ ain, const float* __restrict__ wo,
                          const float* __restrict__ g, const float* __restrict__ bb,
                          float* __restrict__ hs)
{
  int n = blockIdx.x, d = threadIdx.x;
  __shared__ float row[256];
  __shared__ float red[256];
  __shared__ float smean, svar;
  row[d] = ain[n*256+d];
  __syncthreads();
  float s = hs[n*256+d];
  for (int i = 0; i < 256; i++) s += row[i] * wo[i*256+d];
  red[d] = s; __syncthreads();
  for (int off = 128; off; off >>= 1){ if (d < off) red[d] += red[d+off]; __syncthreads(); }
  if (d == 0) smean = red[0] * (1.f/256.f);
  __syncthreads();
  float c = s - smean;
  red[d] = c*c; __syncthreads();
  for (int off = 128; off; off >>= 1){ if (d < off) red[d] += red[d+off]; __syncthreads(); }
  if (d == 0) svar = red[0] * (1.f/256.f);
  __syncthreads();
  hs[n*256+d] = c * rsqrtf(svar + 1e-5f) * g[d] + bb[d];
}

__global__ void k_ff1(const float* __restrict__ hs, const float* __restrict__ w,
                      const float* __restrict__ b, float* __restrict__ h1)
{
  int gid = blockIdx.x*256 + threadIdx.x;
  if (gid >= 64*512) return;
  int n = gid >> 9, j = gid & 511;
  float s = b[j];
  const float* h = hs + n*256;
  for (int i = 0; i < 256; i++) s += h[i] * w[i*512 + j];
  h1[gid] = fmaxf(s, 0.f);
}

__global__ void k_ff2_ln(const float* __restrict__ h1, const float* __restrict__ w,
                         const float* __restrict__ b, const float* __restrict__ g,
                         const float* __restrict__ bb, float* __restrict__ hs)
{
  int n = blockIdx.x, d = threadIdx.x;
  __shared__ float row[512];
  __shared__ float red[256];
  __shared__ float smean, svar;
  row[d] = h1[n*512+d];
  row[d+256] = h1[n*512+256+d];
  __syncthreads();
  float s = hs[n*256+d] + b[d];
  for (int i = 0; i < 512; i++) s += row[i] * w[i*256+d];
  red[d] = s; __syncthreads();
  for (int off = 128; off; off >>= 1){ if (d < off) red[d] += red[d+off]; __syncthreads(); }
  if (d == 0) smean = red[0] * (1.f/256.f);
  __syncthreads();
  float c = s - smean;
  red[d] = c*c; __syncthreads();
  for (int off = 128; off; off >>= 1){ if (d < off) red[d] += red[d+off]; __syncthreads(); }
  if (d == 0) svar = red[0] * (1.f/256.f);
  __syncthreads();
  hs[n*256+d] = c * rsqrtf(svar + 1e-5f) * g[d] + bb[d];
}

__global__ void k_head(const float* __restrict__ hs, const float* __restrict__ fcw,
                       const float* __restrict__ fcb, float* __restrict__ pvec,
                       float* __restrict__ outx)
{
  int n = threadIdx.x; // 64 threads
  float s = fcb[0];
  const float* h = hs + n*256;
  for (int i = 0; i < 256; i++) s += h[i] * fcw[i];
  __shared__ float xs[64];
  xs[n] = s;
  __syncthreads();
  float mx = -1e30f;
  for (int i = 0; i < 64; i++) mx = fmaxf(mx, xs[i]);
  float sum = 0.f;
  for (int i = 0; i < 64; i++) sum += __expf(xs[i]-mx);
  float val = __expf(s-mx)/sum * 64.f;
  val = fminf(val, 3.f);
  pvec[n] = val;
  outx[n] = val;
}

// ---------------- CG helpers ----------------
__global__ void k_dot(const float* __restrict__ a, const float* __restrict__ b,
                      float* __restrict__ scal, int slot, int n)
{
  int gid = blockIdx.x*blockDim.x + threadIdx.x;
  int stride = gridDim.x*blockDim.x;
  float s = 0.f;
  for (int i = gid; i < n; i += stride) s += a[i]*b[i];
  for (int off = 32; off; off >>= 1) s += __shfl_down(s, off, 64);
  __shared__ float wsum[4];
  int lane = threadIdx.x & 63, wv = threadIdx.x >> 6;
  if (lane == 0) wsum[wv] = s;
  __syncthreads();
  if (threadIdx.x == 0) atomicAdd(&scal[slot], wsum[0]+wsum[1]+wsum[2]+wsum[3]);
}

__global__ void k_rinit(const float* __restrict__ b, const float* __restrict__ A,
                        float* __restrict__ r, float* __restrict__ p)
{
  int gid = blockIdx.x*256 + threadIdx.x;
  if (gid < VN){ float v = b[gid] - A[gid]; r[gid] = v; p[gid] = v; }
}

// x += (scal[sa]/scal[sb]) * p;  r -= alpha * Ap   (div folded in)
__global__ void k_xr(float* __restrict__ x, const float* __restrict__ p,
                     float* __restrict__ r, const float* __restrict__ Ap,
                     const float* __restrict__ scal, int sa, int sb)
{
  int gid = blockIdx.x*256 + threadIdx.x;
  if (gid < VN){
    float a = scal[sa] / scal[sb];
    x[gid] += a * p[gid];
    r[gid] -= a * Ap[gid];
  }
}

__global__ void k_pupd(float* __restrict__ p, const float* __restrict__ r,
                       const float* __restrict__ scal, int sa, int sb)
{
  int gid = blockIdx.x*256 + threadIdx.x;
  if (gid < VN){ float b = scal[sa] / scal[sb]; p[gid] = r[gid] + b * p[gid]; }
}

// final CG step fused with ReLU output: out = max(x + alpha*p, 0)
__global__ void k_xfin(const float* __restrict__ x, const float* __restrict__ p,
                       const float* __restrict__ scal, int sa, int sb,
                       float* __restrict__ out)
{
  int gid = blockIdx.x*256 + threadIdx.x;
  if (gid < VN) out[gid] = fmaxf(x[gid] + (scal[sa] / scal[sb]) * p[gid], 0.f);
}

// ---------------- host launch ----------------
extern "C" void kernel_launch(void* const* d_in, const int* in_sizes, int n_in,
                              void* d_out, int out_size, void* d_ws, size_t ws_size,
                              hipStream_t stream)
{
  const float* theta      = (const float*)d_in[0];
  const float* transforms = (const float*)d_in[1];
  const float* slices     = (const float*)d_in[2];
  const float* volume     = (const float*)d_in[3];
  const float* psf        = (const float*)d_in[4];
  const float* idxv       = (const float*)d_in[5];

  char* wsp = (char*)d_ws;
  auto carve = [&](size_t bytes)->void*{
    void* r = (void*)wsp; wsp += (bytes + 255) & ~(size_t)255; return r;
  };
  float* scal = (float*)carve(16*4);
  float* Rm   = (float*)carve(768*4);
  float* pw   = (float*)carve(32*4);
  float* pvec = (float*)carve(64*4);
  float* feat = (float*)carve(16384*4);
  float* hs   = (float*)carve(16384*4);
  float* qkv  = (float*)carve(49152*4);
  float* aout = (float*)carve(16384*4);
  float* h1   = (float*)carve(32768*4);
  float* mask = (float*)carve((size_t)NSL*NPX*4);
  float* volA = (float*)carve((size_t)VN*4);

  size_t used  = (size_t)(wsp - (char*)d_ws);
  size_t avail = (ws_size > used) ? ws_size - used : 0;
  // CG usage in U: r,p,Ap,b vols + sscr + bval + pcor/G
  size_t cgU   = ((size_t)4*VN + 2*(size_t)NSL*NPX + (size_t)PCN)*4;
  auto needU = [&](int cb)->size_t{
    size_t u = ((size_t)VN + 3*(size_t)cb*262144)*4;
    return (u > cgU) ? u : cgU;
  };
  int CB = 8;
  if (avail >= needU(64) + 4096) CB = 64;
  else if (avail >= needU(32) + 4096) CB = 32;

  size_t cbe = (size_t)CB*262144;
  float* U    = (float*)carve(needU(CB));
  float* z    = U;
  float* bufA = U + VN;
  float* bufB = bufA + cbe;
  float* bufC = bufB + cbe;
  float* bvol = U;
  float* rvol = U + VN;
  float* pvol = U + 2*(size_t)VN;
  float* Avol = U + 3*(size_t)VN;
  float* sscr = U + 4*(size_t)VN;
  float* bval = sscr + (size_t)NSL*NPX;
  float* pcor = bval + (size_t)NSL*NPX;   // shared slot: G during forward, pcor during adjoint

  const int PCB = PCN/256;  // exact

  hipMemsetAsync(scal, 0, 64, stream);
  k_prep<<<1, 64, 0, stream>>>(transforms, psf, Rm, pw);
  k_mask<<<4096, 256, 0, stream>>>(slices, mask);
  k_volcopy<<<8192, 256, 0, stream>>>(volume, volA);
  // prologue A(x0)*mask via lattice-factored forward (G in pcor slot; convs
  // will clobber that slot later, after gcorr has consumed it)
  k_gvol<<<PCB, 256, 0, stream>>>(volA, Rm, pcor);
  k_gcorr<<<4096, 256, 0, stream>>>(pcor, pw, mask, nullptr, z, 2*NPX, NPX);
  k_copy0<<<4096, 256, 0, stream>>>(slices, z);

  const float* w6  = (const float*)d_in[6];
  const float* w7  = (const float*)d_in[7];
  const float* w8  = (const float*)d_in[8];
  const float* w9  = (const float*)d_in[9];
  const float* w10 = (const float*)d_in[10];
  const float* w11 = (const float*)d_in[11];
  const float* w12 = (const float*)d_in[12];
  const float* w13 = (const float*)d_in[13];
  const float* w14 = (const float*)d_in[14];

  for (int c = 0; c < 64/CB; c++){
    const float* zc = z + (size_t)c*CB*2*NPX;
    k_convt<7,2,32,2,16><<<CB*16, 256, 0, stream>>>(zc,  w6,  nullptr, bufA, 2,  128, 64,  64, 2, 1, CB, 4);
    k_convd<3,1,32,16,16><<<CB*16, 256, 0, stream>>>(bufA, w7,  nullptr, bufB, 64, 64,  64,  64, 1, 1, CB, 4, 1);
    k_convd<3,1,32,16,16><<<CB*16, 256, 0, stream>>>(bufB, w8,  bufA,    bufC, 64, 64,  64,  64, 1, 1, CB, 4, 1);
    k_convd<3,2,32,16,16><<<CB*8,  256, 0, stream>>>(bufC, w9,  nullptr, bufA, 64, 64,  128, 32, 0, 1, CB, 1, 0);
    k_convd<1,2,32,16,64><<<CB*8,  256, 0, stream>>>(bufC, w11, nullptr, bufB, 64, 64,  128, 32, 0, 0, CB, 1, 0);
    k_convd<3,1,32,16,16><<<CB*8,  256, 0, stream>>>(bufA, w10, bufB,    bufC, 128,32,  128, 32, 1, 1, CB, 1, 0);
    k_convd<3,2,16,8,32><<<(CB/4)*32, 256, 0, stream>>>(bufC, w12, nullptr, bufA, 128, 32, 256, 16, 0, 1, CB/4, 1, 0);
    k_convd<1,2,16,8,128><<<(CB/4)*32, 256, 0, stream>>>(bufC, w14, nullptr, bufB, 128, 32, 256, 16, 0, 0, CB/4, 1, 0);
    k_convd<3,1,16,8,32><<<(CB/4)*32, 256, 0, stream>>>(bufA, w13, bufB,    bufC, 256, 16, 256, 16, 1, 1, CB/4, 1, 0);
    k_pool<<<CB, 256, 0, stream>>>(bufC, feat + (size_t)c*CB*256, CB*256);
  }

  k_pe<<<64, 256, 0, stream>>>(feat, theta, idxv, (const float*)d_in[15], (const float*)d_in[16], hs);
  for (int l = 0; l < 4; l++){
    k_qkv<<<192, 256, 0, stream>>>(hs, (const float*)d_in[17] + (size_t)l*65536,
                                       (const float*)d_in[18] + (size_t)l*65536,
                                       (const float*)d_in[19] + (size_t)l*65536, qkv);
    k_attn<<<4, 256, 0, stream>>>(qkv, aout);
    k_proj_ln<<<64, 256, 0, stream>>>(aout, (const float*)d_in[20] + (size_t)l*65536,
                                      (const float*)d_in[21] + l*256, (const float*)d_in[22] + l*256, hs);
    k_ff1<<<128, 256, 0, stream>>>(hs, (const float*)d_in[23] + (size_t)l*131072,
                                   (const float*)d_in[24] + l*512, h1);
    k_ff2_ln<<<64, 256, 0, stream>>>(h1, (const float*)d_in[25] + (size_t)l*131072,
                                     (const float*)d_in[26] + l*256, (const float*)d_in[27] + l*256,
                                     (const float*)d_in[28] + l*256, hs);
  }
  k_head<<<1, 64, 0, stream>>>(hs, (const float*)d_in[29], (const float*)d_in[30], pvec,
                               (float*)d_out + VN);

  // ---- CG ----
  k_zscale<<<4096, 256, 0, stream>>>(z, pvec, sscr);
  k_premul<<<4096, 256, 0, stream>>>(slices, mask, pvec, bval);
  k_pcorr<<<PCB, 256, 0, stream>>>(bval, pw, pcor);
  k_sadj<<<8192, 256, 0, stream>>>(pcor, Rm, bvol);                 // b = At(slices*p)
  k_pcorr<<<PCB, 256, 0, stream>>>(sscr, pw, pcor);
  k_sadj<<<8192, 256, 0, stream>>>(pcor, Rm, Avol);                 // AtA(x0)
  k_rinit<<<8192, 256, 0, stream>>>(bvol, Avol, rvol, pvol);
  k_dot<<<512, 256, 0, stream>>>(rvol, rvol, scal, 0, VN);          // rr0
  // iter 1
  k_gvol<<<PCB, 256, 0, stream>>>(pvol, Rm, pcor);                  // G(p)
  k_gcorr<<<4096, 256, 0, stream>>>(pcor, pw, mask, pvec, sscr, NPX, 0);
  k_pcorr<<<PCB, 256, 0, stream>>>(sscr, pw, pcor);                 // overwrites G (safe)
  k_sadj<<<8192, 256, 0, stream>>>(pcor, Rm, Avol);
  k_dot<<<512, 256, 0, stream>>>(pvol, Avol, scal, 1, VN);          // pAp1
  k_xr<<<8192, 256, 0, stream>>>(volA, pvol, rvol, Avol, scal, 0, 1);
  k_dot<<<512, 256, 0, stream>>>(rvol, rvol, scal, 3, VN);          // rr1
  k_pupd<<<8192, 256, 0, stream>>>(pvol, rvol, scal, 3, 0);         // beta = rr1/rr0
  // iter 2
  k_gvol<<<PCB, 256, 0, stream>>>(pvol, Rm, pcor);
  k_gcorr<<<4096, 256, 0, stream>>>(pcor, pw, mask, pvec, sscr, NPX, 0);
  k_pcorr<<<PCB, 256, 0, stream>>>(sscr, pw, pcor);
  k_sadj<<<8192, 256, 0, stream>>>(pcor, Rm, Avol);
  k_dot<<<512, 256, 0, stream>>>(pvol, Avol, scal, 5, VN);          // pAp2
  k_xfin<<<8192, 256, 0, stream>>>(volA, pvol, scal, 3, 5, (float*)d_out);
}